// Round 1
// baseline (1267.347 us; speedup 1.0000x reference)
//
#include <hip/hip_runtime.h>
#include <math.h>

#define B_  32
#define L_  1024
#define M_  (B_*L_)      // 32768 rows
#define DM  128
#define DI  256
#define DS  16
#define DC  4
#define DR  8
#define NL  2

__device__ __forceinline__ float silu_f(float x) { return x / (1.f + expf(-x)); }
__device__ __forceinline__ float softplus_f(float x) {
    // logaddexp(x, 0) = max(x,0) + log1p(exp(-|x|)) (matches jax.nn.softplus)
    return fmaxf(x, 0.f) + log1pf(expf(-fabsf(x)));
}

// ---------------------------------------------------------------- embed
// out[b,t,d] = sum_{w,f} x_enc[b, wrap(t+w-1), f]*tokW[d,f,w]
//            + sum_f x_mark[b,t,f]*tempW[d,f] + PE(t,d)
__global__ __launch_bounds__(256) void embed_kernel(
        const float* __restrict__ x_enc, const float* __restrict__ x_mark,
        const float* __restrict__ tokW, const float* __restrict__ tempW,
        float* __restrict__ out) {
    int idx = blockIdx.x * 256 + threadIdx.x;      // over M_*DM
    int d = idx & 127;
    int m = idx >> 7;
    int b = m >> 10, t = m & 1023;
    const float* xb = x_enc + (size_t)b * L_ * 7;
    float acc = 0.f;
    #pragma unroll
    for (int w = 0; w < 3; ++w) {
        int tt = t + w - 1;
        tt = (tt < 0) ? (L_ - 1) : (tt >= L_ ? 0 : tt);   // circular pad
        const float* xr = xb + tt * 7;
        #pragma unroll
        for (int f = 0; f < 7; ++f) acc += xr[f] * tokW[(d * 7 + f) * 3 + w];
    }
    const float* mr = x_mark + (size_t)m * 4;
    #pragma unroll
    for (int f = 0; f < 4; ++f) acc += mr[f] * tempW[d * 4 + f];
    // positional embedding: pe[t,2i]=sin(t*div_i), pe[t,2i+1]=cos(t*div_i)
    int i2 = d & ~1;
    float div = expf(-0.07195578415606394f * (float)i2);  // -ln(10000)/128
    float ang = (float)t * div;
    acc += (d & 1) ? cosf(ang) : sinf(ang);
    out[idx] = acc;
}

// ---------------------------------------------------------------- layernorm
// res = a (+ b);  optionally store res;  out_ln = LN(res)*w + bias
// one wave per 128-wide row, 2 elements/lane
__global__ __launch_bounds__(256) void ln_kernel(
        const float* __restrict__ a, const float* __restrict__ b,
        const float* __restrict__ w, const float* __restrict__ bias,
        float* __restrict__ out_ln, float* __restrict__ out_res) {
    int wv = threadIdx.x >> 6, lane = threadIdx.x & 63;
    size_t m = (size_t)blockIdx.x * 4 + wv;
    size_t base = m * DM;
    float x0 = a[base + lane], x1 = a[base + lane + 64];
    if (b) { x0 += b[base + lane]; x1 += b[base + lane + 64]; }
    if (out_res) { out_res[base + lane] = x0; out_res[base + lane + 64] = x1; }
    float s = x0 + x1;
    #pragma unroll
    for (int o = 1; o < 64; o <<= 1) s += __shfl_xor(s, o, 64);
    float mu = s * (1.f / 128.f);
    float d0 = x0 - mu, d1 = x1 - mu;
    float v = d0 * d0 + d1 * d1;
    #pragma unroll
    for (int o = 1; o < 64; o <<= 1) v += __shfl_xor(v, o, 64);
    float inv = rsqrtf(v * (1.f / 128.f) + 1e-5f);
    out_ln[base + lane]      = d0 * inv * w[lane]      + bias[lane];
    out_ln[base + lane + 64] = d1 * inv * w[lane + 64] + bias[lane + 64];
}

// ---------------------------------------------------------------- GEMM (fp32)
// C[m,n] = sum_k A[m,k] * W[n,k];  A: MxK row-major, W: NxK row-major
// 64x64 tile, BK=16, 256 threads, 4x4 per thread
__global__ __launch_bounds__(256) void gemm_nt(
        const float* __restrict__ A, const float* __restrict__ W,
        float* __restrict__ C, int M, int N, int K) {
    __shared__ float As[16][68];   // [k][m], +4 pad: 2-way conflicts only
    __shared__ float Ws[16][68];   // [k][n]
    int bm = blockIdx.y * 64, bn = blockIdx.x * 64;
    int tid = threadIdx.x;
    int tx = tid & 15, ty = tid >> 4;     // tx -> n, ty -> m
    float acc[4][4] = {};
    for (int k0 = 0; k0 < K; k0 += 16) {
        #pragma unroll
        for (int i = 0; i < 4; ++i) {
            int r = i * 16 + ty;
            As[tx][r] = A[(size_t)(bm + r) * K + k0 + tx];
            int n = bn + r;
            Ws[tx][r] = (n < N) ? W[(size_t)n * K + k0 + tx] : 0.f;
        }
        __syncthreads();
        #pragma unroll
        for (int k = 0; k < 16; ++k) {
            float a[4], bb[4];
            #pragma unroll
            for (int i = 0; i < 4; ++i) a[i] = As[k][ty * 4 + i];
            #pragma unroll
            for (int j = 0; j < 4; ++j) bb[j] = Ws[k][tx * 4 + j];
            #pragma unroll
            for (int i = 0; i < 4; ++i)
                #pragma unroll
                for (int j = 0; j < 4; ++j) acc[i][j] += a[i] * bb[j];
        }
        __syncthreads();
    }
    #pragma unroll
    for (int i = 0; i < 4; ++i) {
        int m = bm + ty * 4 + i;
        #pragma unroll
        for (int j = 0; j < 4; ++j) {
            int n = bn + tx * 4 + j;
            if (n < N) C[(size_t)m * N + n] = acc[i][j];
        }
    }
}

// ---------------------------------------------------------------- depthwise conv + silu
// u[b,t,d] = silu( sum_{w=0..3} xi[b,t-3+w,d]*cw[d,w] + cb[d] ),  xi = xz[...,0:256]
__global__ __launch_bounds__(256) void conv_silu_kernel(
        const float* __restrict__ xz, const float* __restrict__ cw,
        const float* __restrict__ cb, float* __restrict__ u) {
    int idx = blockIdx.x * 256 + threadIdx.x;    // over M_*DI
    int d = idx & 255;
    long m = idx >> 8;
    int t = (int)(m & 1023);
    long rowbase = m * 512 + d;
    float4 w4 = ((const float4*)cw)[d];
    float acc = cb[d];
    const float wk[4] = {w4.x, w4.y, w4.z, w4.w};
    #pragma unroll
    for (int w = 0; w < 4; ++w) {
        int tt = t - 3 + w;
        if (tt >= 0) acc += xz[rowbase + (long)(w - 3) * 512] * wk[w];
    }
    u[idx] = silu_f(acc);
}

// ---------------------------------------------------------------- dt projection + softplus
// dt[m,n] = softplus( sum_{k<8} dbc[m,k]*dtW[n,k] + dtb[n] )
__global__ __launch_bounds__(256) void dt_kernel(
        const float* __restrict__ dbc, const float* __restrict__ dtW,
        const float* __restrict__ dtb, float* __restrict__ dt) {
    int n = threadIdx.x;                 // 0..255
    float4 wa = ((const float4*)dtW)[n * 2];
    float4 wb = ((const float4*)dtW)[n * 2 + 1];
    float bias = dtb[n];
    size_t m0 = (size_t)blockIdx.x * 64;
    for (int r = 0; r < 64; ++r) {
        const float* row = dbc + (m0 + r) * 40;
        float acc = bias;
        acc += row[0] * wa.x + row[1] * wa.y + row[2] * wa.z + row[3] * wa.w;
        acc += row[4] * wb.x + row[5] * wb.y + row[6] * wb.z + row[7] * wb.w;
        dt[(m0 + r) * 256 + n] = softplus_f(acc);
    }
}

// ---------------------------------------------------------------- selective scan
// block = 256 threads = 16 d x 16 s ; grid = 32 b x 16 d-groups
// h[b,d,s](t) = exp(dt*A)*h(t-1) + dt*B[b,t,s]*u[b,t,d];  y[b,t,d] = sum_s h*C[b,t,s]
__global__ __launch_bounds__(256) void scan_kernel(
        const float* __restrict__ dt, const float* __restrict__ dbc,
        const float* __restrict__ u, const float* __restrict__ A_log,
        float* __restrict__ ys) {
    int b = blockIdx.x >> 4, dg = blockIdx.x & 15;
    int tid = threadIdx.x;
    int row = tid >> 4, col = tid & 15;    // staging map
    int dl = tid >> 4, s = tid & 15;       // compute map
    int d = dg * 16 + dl;
    float A = -expf(A_log[d * 16 + s]);
    float h = 0.f;
    __shared__ float sdt[64][16], su[64][16], sB[64][16], sC[64][16];
    size_t mb = (size_t)b * 1024;
    for (int t0 = 0; t0 < 1024; t0 += 64) {
        __syncthreads();
        #pragma unroll
        for (int i = 0; i < 4; ++i) {
            int tt = i * 16 + row;
            size_t g = mb + t0 + tt;
            sdt[tt][col] = dt[g * 256 + dg * 16 + col];
            su[tt][col]  = u[g * 256 + dg * 16 + col];
            sB[tt][col]  = dbc[g * 40 + 8 + col];
            sC[tt][col]  = dbc[g * 40 + 24 + col];
        }
        __syncthreads();
        for (int tt = 0; tt < 64; ++tt) {
            float dtv = sdt[tt][dl];
            float uv  = su[tt][dl];
            float bv  = sB[tt][s];
            float cv  = sC[tt][s];
            float dA = expf(dtv * A);
            h = dA * h + dtv * bv * uv;
            float p = h * cv;
            p += __shfl_xor(p, 1, 64);
            p += __shfl_xor(p, 2, 64);
            p += __shfl_xor(p, 4, 64);
            p += __shfl_xor(p, 8, 64);
            if (s == 0) ys[(mb + t0 + tt) * 256 + d] = p;
        }
    }
}

// ---------------------------------------------------------------- gating
// ys[m,e] = (ys[m,e] + u[m,e]*D[e]) * silu(z[m,e]),  z = xz[m, 256+e]
__global__ __launch_bounds__(256) void gate_kernel(
        float* __restrict__ ys, const float* __restrict__ u,
        const float* __restrict__ xz, const float* __restrict__ Dp) {
    int idx = blockIdx.x * 256 + threadIdx.x;
    int e = idx & 255;
    size_t m = (size_t)(idx >> 8);
    float z = xz[m * 512 + 256 + e];
    ys[idx] = (ys[idx] + u[idx] * Dp[e]) * silu_f(z);
}

// ---------------------------------------------------------------- final projection (C_OUT=7)
__global__ __launch_bounds__(256) void outproj_kernel(
        const float* __restrict__ x, const float* __restrict__ W,
        float* __restrict__ out) {
    int wv = threadIdx.x >> 6, lane = threadIdx.x & 63;
    size_t m = (size_t)blockIdx.x * 4 + wv;
    float x0 = x[m * 128 + lane], x1 = x[m * 128 + lane + 64];
    #pragma unroll
    for (int c = 0; c < 7; ++c) {
        float p = x0 * W[c * 128 + lane] + x1 * W[c * 128 + lane + 64];
        #pragma unroll
        for (int o = 1; o < 64; o <<= 1) p += __shfl_xor(p, o, 64);
        if (lane == 0) out[m * 7 + c] = p;
    }
}

// ================================================================ launch
extern "C" void kernel_launch(void* const* d_in, const int* in_sizes, int n_in,
                              void* d_out, int out_size, void* d_ws, size_t ws_size,
                              hipStream_t stream) {
    const float* x_enc  = (const float*)d_in[0];
    const float* x_mark = (const float*)d_in[1];
    const float* tokW   = (const float*)d_in[4];
    const float* tempW  = (const float*)d_in[5];
    const float* norm_w = (const float*)d_in[6];
    const float* norm_b = (const float*)d_in[7];
    const float* inW    = (const float*)d_in[8];
    const float* convW  = (const float*)d_in[9];
    const float* convB  = (const float*)d_in[10];
    const float* xpW    = (const float*)d_in[11];
    const float* dtW    = (const float*)d_in[12];
    const float* dtbp   = (const float*)d_in[13];
    const float* A_log  = (const float*)d_in[14];
    const float* Dp     = (const float*)d_in[15];
    const float* outW   = (const float*)d_in[16];
    const float* nfw    = (const float*)d_in[17];
    const float* nfb    = (const float*)d_in[18];
    const float* finW   = (const float*)d_in[19];
    float* out = (float*)d_out;

    float* ws = (float*)d_ws;
    size_t o = 0;
    float* hidden   = ws + o; o += (size_t)M_ * DM;    // 16.8 MB
    float* residual = ws + o; o += (size_t)M_ * DM;    // 16.8 MB
    float* xln      = ws + o; o += (size_t)M_ * DM;    // 16.8 MB
    float* xz       = ws + o; o += (size_t)M_ * 512;   // 67 MB
    float* ubuf     = ws + o; o += (size_t)M_ * DI;    // 33.5 MB
    float* dbc      = ws + o; o += (size_t)M_ * 40;    // 5.2 MB
    float* dtbuf    = ws + o; o += (size_t)M_ * DI;    // 33.5 MB
    float* ysb      = ws + o; o += (size_t)M_ * DI;    // 33.5 MB

    dim3 blk(256);
    embed_kernel<<<M_ * DM / 256, blk, 0, stream>>>(x_enc, x_mark, tokW, tempW, hidden);

    for (int l = 0; l < NL; ++l) {
        // residual = hidden (+ old residual);  xln = LN(residual)
        ln_kernel<<<M_ / 4, blk, 0, stream>>>(hidden, l ? residual : nullptr,
                                              norm_w + l * DM, norm_b + l * DM,
                                              xln, residual);
        // xz = xln @ in_W^T   (M x 512, K=128)
        dim3 g1(8, M_ / 64);
        gemm_nt<<<g1, blk, 0, stream>>>(xln, inW + (size_t)l * 512 * DM, xz, M_, 512, DM);
        // u = silu(causal depthwise conv(xi)) ; xi = xz[...,:256]
        conv_silu_kernel<<<M_ * DI / 256, blk, 0, stream>>>(xz, convW + l * DI * DC,
                                                            convB + l * DI, ubuf);
        // dbc = u @ xp_W^T    (M x 40, K=256)
        dim3 g2(1, M_ / 64);
        gemm_nt<<<g2, blk, 0, stream>>>(ubuf, xpW + (size_t)l * 40 * DI, dbc, M_, 40, DI);
        // dt = softplus(dbc[:, :8] @ dtW^T + dtb)
        dt_kernel<<<M_ / 64, blk, 0, stream>>>(dbc, dtW + l * DI * DR, dtbp + l * DI, dtbuf);
        // selective scan -> ys
        scan_kernel<<<B_ * 16, blk, 0, stream>>>(dtbuf, dbc, ubuf,
                                                 A_log + l * DI * DS, ysb);
        // ys = (ys + u*D) * silu(z)
        gate_kernel<<<M_ * DI / 256, blk, 0, stream>>>(ysb, ubuf, xz, Dp + l * DI);
        // hidden = ys @ out_W^T  (M x 128, K=256)
        dim3 g3(2, M_ / 64);
        gemm_nt<<<g3, blk, 0, stream>>>(ysb, outW + (size_t)l * DM * DI, hidden, M_, DM, DI);
    }

    // final LN(hidden + residual), then out = xln @ out_W^T (7 x 128)
    ln_kernel<<<M_ / 4, blk, 0, stream>>>(hidden, residual, nfw, nfb, xln, nullptr);
    outproj_kernel<<<M_ / 4, blk, 0, stream>>>(xln, finW, out);
}

// Round 2
// 862.477 us; speedup vs baseline: 1.4694x; 1.4694x over previous
//
#include <hip/hip_runtime.h>
#include <math.h>

#define B_  32
#define L_  1024
#define M_  (B_*L_)      // 32768 rows
#define DM  128
#define DI  256
#define DS  16
#define DC  4
#define DR  8
#define NL  2

__device__ __forceinline__ float silu_f(float x) { return x / (1.f + expf(-x)); }
__device__ __forceinline__ float softplus_f(float x) {
    return fmaxf(x, 0.f) + log1pf(expf(-fabsf(x)));
}

// ---------------------------------------------------------------- embed
__global__ __launch_bounds__(256) void embed_kernel(
        const float* __restrict__ x_enc, const float* __restrict__ x_mark,
        const float* __restrict__ tokW, const float* __restrict__ tempW,
        float* __restrict__ out) {
    int idx = blockIdx.x * 256 + threadIdx.x;      // over M_*DM
    int d = idx & 127;
    int m = idx >> 7;
    int b = m >> 10, t = m & 1023;
    const float* xb = x_enc + (size_t)b * L_ * 7;
    float acc = 0.f;
    #pragma unroll
    for (int w = 0; w < 3; ++w) {
        int tt = t + w - 1;
        tt = (tt < 0) ? (L_ - 1) : (tt >= L_ ? 0 : tt);   // circular pad
        const float* xr = xb + tt * 7;
        #pragma unroll
        for (int f = 0; f < 7; ++f) acc += xr[f] * tokW[(d * 7 + f) * 3 + w];
    }
    const float* mr = x_mark + (size_t)m * 4;
    #pragma unroll
    for (int f = 0; f < 4; ++f) acc += mr[f] * tempW[d * 4 + f];
    int i2 = d & ~1;
    float div = expf(-0.07195578415606394f * (float)i2);  // -ln(10000)/128
    float ang = (float)t * div;
    acc += (d & 1) ? cosf(ang) : sinf(ang);
    out[idx] = acc;
}

// ---------------------------------------------------------------- layernorm
__global__ __launch_bounds__(256) void ln_kernel(
        const float* __restrict__ a, const float* __restrict__ b,
        const float* __restrict__ w, const float* __restrict__ bias,
        float* __restrict__ out_ln, float* __restrict__ out_res) {
    int wv = threadIdx.x >> 6, lane = threadIdx.x & 63;
    size_t m = (size_t)blockIdx.x * 4 + wv;
    size_t base = m * DM;
    float x0 = a[base + lane], x1 = a[base + lane + 64];
    if (b) { x0 += b[base + lane]; x1 += b[base + lane + 64]; }
    if (out_res) { out_res[base + lane] = x0; out_res[base + lane + 64] = x1; }
    float s = x0 + x1;
    #pragma unroll
    for (int o = 1; o < 64; o <<= 1) s += __shfl_xor(s, o, 64);
    float mu = s * (1.f / 128.f);
    float d0 = x0 - mu, d1 = x1 - mu;
    float v = d0 * d0 + d1 * d1;
    #pragma unroll
    for (int o = 1; o < 64; o <<= 1) v += __shfl_xor(v, o, 64);
    float inv = rsqrtf(v * (1.f / 128.f) + 1e-5f);
    out_ln[base + lane]      = d0 * inv * w[lane]      + bias[lane];
    out_ln[base + lane + 64] = d1 * inv * w[lane + 64] + bias[lane + 64];
}

// ---------------------------------------------------------------- GEMM 128x128 (fp32, A normal)
// C[m,n] = sum_k A[m,k]*W[n,k]; 256 thr, 8x8/thread, BK=16. M%128==0, N%128==0.
__global__ __launch_bounds__(256) void gemm_nt_128(
        const float* __restrict__ A, const float* __restrict__ W,
        float* __restrict__ C, int M, int N, int K) {
    __shared__ float As[16][128];
    __shared__ float Ws[16][128];
    int bm = blockIdx.y * 128, bn = blockIdx.x * 128;
    int tid = threadIdx.x, tx = tid & 15, ty = tid >> 4;
    float acc[8][8] = {};
    for (int k0 = 0; k0 < K; k0 += 16) {
        #pragma unroll
        for (int i = 0; i < 2; ++i) {
            int idx = tid * 2 + i;            // 0..511
            int row = idx >> 2, c4 = (idx & 3) * 4;
            float4 a4 = *(const float4*)(A + (size_t)(bm + row) * K + k0 + c4);
            As[c4 + 0][row] = a4.x; As[c4 + 1][row] = a4.y;
            As[c4 + 2][row] = a4.z; As[c4 + 3][row] = a4.w;
            float4 w4 = *(const float4*)(W + (size_t)(bn + row) * K + k0 + c4);
            Ws[c4 + 0][row] = w4.x; Ws[c4 + 1][row] = w4.y;
            Ws[c4 + 2][row] = w4.z; Ws[c4 + 3][row] = w4.w;
        }
        __syncthreads();
        #pragma unroll
        for (int k = 0; k < 16; ++k) {
            float a[8], bb[8];
            *(float4*)&a[0]  = *(float4*)&As[k][ty * 8];
            *(float4*)&a[4]  = *(float4*)&As[k][ty * 8 + 4];
            *(float4*)&bb[0] = *(float4*)&Ws[k][tx * 8];
            *(float4*)&bb[4] = *(float4*)&Ws[k][tx * 8 + 4];
            #pragma unroll
            for (int i = 0; i < 8; ++i)
                #pragma unroll
                for (int j = 0; j < 8; ++j) acc[i][j] += a[i] * bb[j];
        }
        __syncthreads();
    }
    #pragma unroll
    for (int i = 0; i < 8; ++i) {
        size_t row = (size_t)(bm + ty * 8 + i) * N + bn + tx * 8;
        *(float4*)(C + row)     = *(float4*)&acc[i][0];
        *(float4*)(C + row + 4) = *(float4*)&acc[i][4];
    }
}

// ---------------------------------------------------------------- GEMM 128x128 (A transposed: A_T[(b*K)+e][t])
// C[m,n] = sum_e A_T[(b*K+e)*1024 + t] * W[n,e], m=b*1024+t. K=256 here.
__global__ __launch_bounds__(256) void gemm_tn_128(
        const float* __restrict__ AT, const float* __restrict__ W,
        float* __restrict__ C, int M, int N, int K) {
    __shared__ float As[16][128];
    __shared__ float Ws[16][128];
    int bm = blockIdx.y * 128, bn = blockIdx.x * 128;
    int b = bm >> 10, tloc = bm & 1023;
    int tid = threadIdx.x, tx = tid & 15, ty = tid >> 4;
    float acc[8][8] = {};
    for (int k0 = 0; k0 < K; k0 += 16) {
        #pragma unroll
        for (int i = 0; i < 2; ++i) {
            int idx = tid * 2 + i;            // 0..511
            int k = idx >> 5, m4 = (idx & 31) * 4;
            float4 a4 = *(const float4*)(AT + ((size_t)b * K + k0 + k) * 1024 + tloc + m4);
            *(float4*)&As[k][m4] = a4;
            int row = idx >> 2, c4 = (idx & 3) * 4;
            float4 w4 = *(const float4*)(W + (size_t)(bn + row) * K + k0 + c4);
            Ws[c4 + 0][row] = w4.x; Ws[c4 + 1][row] = w4.y;
            Ws[c4 + 2][row] = w4.z; Ws[c4 + 3][row] = w4.w;
        }
        __syncthreads();
        #pragma unroll
        for (int k = 0; k < 16; ++k) {
            float a[8], bb[8];
            *(float4*)&a[0]  = *(float4*)&As[k][ty * 8];
            *(float4*)&a[4]  = *(float4*)&As[k][ty * 8 + 4];
            *(float4*)&bb[0] = *(float4*)&Ws[k][tx * 8];
            *(float4*)&bb[4] = *(float4*)&Ws[k][tx * 8 + 4];
            #pragma unroll
            for (int i = 0; i < 8; ++i)
                #pragma unroll
                for (int j = 0; j < 8; ++j) acc[i][j] += a[i] * bb[j];
        }
        __syncthreads();
    }
    #pragma unroll
    for (int i = 0; i < 8; ++i) {
        size_t row = (size_t)(bm + ty * 8 + i) * N + bn + tx * 8;
        *(float4*)(C + row)     = *(float4*)&acc[i][0];
        *(float4*)(C + row + 4) = *(float4*)&acc[i][4];
    }
}

// ---------------------------------------------------------------- GEMM 64x64 (A transposed), N small w/ guard
__global__ __launch_bounds__(256) void gemm_tn_64(
        const float* __restrict__ AT, const float* __restrict__ W,
        float* __restrict__ C, int M, int N, int K) {
    __shared__ float As[16][68];
    __shared__ float Ws[16][68];
    int bm = blockIdx.y * 64, bn = blockIdx.x * 64;
    int b = bm >> 10, tloc = bm & 1023;
    int tid = threadIdx.x, tx = tid & 15, ty = tid >> 4;
    float acc[4][4] = {};
    for (int k0 = 0; k0 < K; k0 += 16) {
        {
            int k = tid >> 4, m4 = (tid & 15) * 4;
            float4 a4 = *(const float4*)(AT + ((size_t)b * K + k0 + k) * 1024 + tloc + m4);
            *(float4*)&As[k][m4] = a4;
        }
        #pragma unroll
        for (int i = 0; i < 4; ++i) {
            int r = i * 16 + ty;
            int n = bn + r;
            Ws[tx][r] = (n < N) ? W[(size_t)n * K + k0 + tx] : 0.f;
        }
        __syncthreads();
        #pragma unroll
        for (int k = 0; k < 16; ++k) {
            float a[4], bb[4];
            #pragma unroll
            for (int i = 0; i < 4; ++i) a[i] = As[k][ty * 4 + i];
            #pragma unroll
            for (int j = 0; j < 4; ++j) bb[j] = Ws[k][tx * 4 + j];
            #pragma unroll
            for (int i = 0; i < 4; ++i)
                #pragma unroll
                for (int j = 0; j < 4; ++j) acc[i][j] += a[i] * bb[j];
        }
        __syncthreads();
    }
    #pragma unroll
    for (int i = 0; i < 4; ++i) {
        int m = bm + ty * 4 + i;
        #pragma unroll
        for (int j = 0; j < 4; ++j) {
            int n = bn + tx * 4 + j;
            if (n < N) C[(size_t)m * N + n] = acc[i][j];
        }
    }
}

// ---------------------------------------------------------------- conv + silu -> uT
// uT[(b*256+d)*1024 + t] = silu(conv(xz[...,:256])) ; LDS-tiled (64t x 64d per block)
__global__ __launch_bounds__(256) void conv_uT_kernel(
        const float* __restrict__ xz, const float* __restrict__ cw,
        const float* __restrict__ cb, float* __restrict__ uT) {
    __shared__ float xs[67][64];
    int bx = blockIdx.x;
    int d0 = (bx & 3) * 64;
    int t0 = ((bx >> 2) & 15) * 64;
    int b = bx >> 6;
    int tid = threadIdx.x;
    {
        int row = tid >> 2, q = tid & 3;
        int t = t0 - 3 + row;
        const float* src = xz + ((size_t)(b * 1024 + t)) * 512 + d0 + q * 16;
        #pragma unroll
        for (int j = 0; j < 4; ++j) {
            float4 v = (t >= 0) ? *(const float4*)(src + j * 4)
                                : make_float4(0.f, 0.f, 0.f, 0.f);
            *(float4*)&xs[row][q * 16 + j * 4] = v;
        }
        if (tid < 12) {
            int row2 = 64 + (tid >> 2);
            int t2 = t0 - 3 + row2;               // >= 61, always valid
            const float* s2 = xz + ((size_t)(b * 1024 + t2)) * 512 + d0 + q * 16;
            #pragma unroll
            for (int j = 0; j < 4; ++j)
                *(float4*)&xs[row2][q * 16 + j * 4] = *(const float4*)(s2 + j * 4);
        }
    }
    __syncthreads();
    int dl = tid & 63, tl = tid >> 6;
    float4 w4 = ((const float4*)cw)[d0 + dl];
    float bias = cb[d0 + dl];
    float* dst = uT + ((size_t)(b * 256 + d0 + dl)) * 1024 + t0 + tl * 16;
    #pragma unroll
    for (int c = 0; c < 4; ++c) {
        float r[4];
        #pragma unroll
        for (int i = 0; i < 4; ++i) {
            int tt = tl * 16 + c * 4 + i;
            float acc = bias + xs[tt][dl] * w4.x + xs[tt + 1][dl] * w4.y
                             + xs[tt + 2][dl] * w4.z + xs[tt + 3][dl] * w4.w;
            r[i] = silu_f(acc);
        }
        *(float4*)(dst + c * 4) = make_float4(r[0], r[1], r[2], r[3]);
    }
}

// ---------------------------------------------------------------- dt proj + softplus -> dtT
__global__ __launch_bounds__(256) void dtT_kernel(
        const float* __restrict__ dbc, const float* __restrict__ dtW,
        const float* __restrict__ dtb, float* __restrict__ dtT) {
    int n = threadIdx.x;
    int m0 = blockIdx.x * 64;
    int b = m0 >> 10, t0 = m0 & 1023;
    float4 wa = ((const float4*)dtW)[n * 2];
    float4 wb = ((const float4*)dtW)[n * 2 + 1];
    float bias = dtb[n];
    float* dst = dtT + ((size_t)(b * 256 + n)) * 1024 + t0;
    for (int r4 = 0; r4 < 64; r4 += 4) {
        float o[4];
        #pragma unroll
        for (int i = 0; i < 4; ++i) {
            const float* row = dbc + (size_t)(m0 + r4 + i) * 40;
            float acc = bias + row[0] * wa.x + row[1] * wa.y + row[2] * wa.z + row[3] * wa.w
                             + row[4] * wb.x + row[5] * wb.y + row[6] * wb.z + row[7] * wb.w;
            o[i] = softplus_f(acc);
        }
        *(float4*)(dst + r4) = make_float4(o[0], o[1], o[2], o[3]);
    }
}

// ---------------------------------------------------------------- dbc -> BT, CT (transpose)
__global__ __launch_bounds__(256) void tbc_kernel(
        const float* __restrict__ dbc, float* __restrict__ BT, float* __restrict__ CT) {
    __shared__ float tile[128][33];
    int b = blockIdx.x >> 3, t0 = (blockIdx.x & 7) * 128;
    int tid = threadIdx.x;
    {
        int t = tid >> 1, half = tid & 1;
        const float* src = dbc + (size_t)(b * 1024 + t0 + t) * 40 + 8 + half * 16;
        #pragma unroll
        for (int c = 0; c < 4; ++c) {
            float4 v = *(const float4*)(src + c * 4);
            int c0 = half * 16 + c * 4;
            tile[t][c0 + 0] = v.x; tile[t][c0 + 1] = v.y;
            tile[t][c0 + 2] = v.z; tile[t][c0 + 3] = v.w;
        }
    }
    __syncthreads();
    int row = tid >> 3, q = tid & 7;
    float* dst = ((row < 16) ? BT : CT) + ((size_t)(b * 16 + (row & 15))) * 1024 + t0 + q * 16;
    #pragma unroll
    for (int c = 0; c < 4; ++c) {
        int i0 = q * 16 + c * 4;
        float4 w = make_float4(tile[i0][row], tile[i0 + 1][row],
                               tile[i0 + 2][row], tile[i0 + 3][row]);
        *(float4*)(dst + c * 4) = w;
    }
}

// ---------------------------------------------------------------- scan v2 (wave-parallel chunked scan)
// one wave per (b,d); lane j owns t in [16j,16j+16); Kogge-Stone over 64 lanes per state s.
// fuses gate: yT = (scan_y + u*D) * silu(z)
__global__ __launch_bounds__(256) void scan2_kernel(
        const float* __restrict__ dtT, const float* __restrict__ uT,
        const float* __restrict__ BT, const float* __restrict__ CT,
        const float* __restrict__ A_log, const float* __restrict__ xz,
        const float* __restrict__ Dp, float* __restrict__ yT) {
    int wid = blockIdx.x * 4 + (threadIdx.x >> 6);   // b*256 + d
    int b = wid >> 8, d = wid & 255;
    int lane = threadIdx.x & 63;
    size_t base = (size_t)wid * 1024 + lane * 16;

    float dt[16], du[16], y[16];
    {
        const float4* p = (const float4*)(dtT + base);
        const float4* q = (const float4*)(uT + base);
        #pragma unroll
        for (int c = 0; c < 4; ++c) {
            float4 dv = p[c], uv = q[c];
            dt[c * 4 + 0] = dv.x; dt[c * 4 + 1] = dv.y; dt[c * 4 + 2] = dv.z; dt[c * 4 + 3] = dv.w;
            du[c * 4 + 0] = dv.x * uv.x; du[c * 4 + 1] = dv.y * uv.y;
            du[c * 4 + 2] = dv.z * uv.z; du[c * 4 + 3] = dv.w * uv.w;
        }
        #pragma unroll
        for (int i = 0; i < 16; ++i) y[i] = 0.f;
    }
    size_t bcbase = ((size_t)b * 16) * 1024 + lane * 16;

    for (int s = 0; s < 16; ++s) {
        float A2 = -expf(A_log[d * 16 + s]) * 1.4426950408889634f;  // A * log2(e)
        float Bv[16], Cv[16], PC[16];
        {
            const float4* pB = (const float4*)(BT + bcbase + (size_t)s * 1024);
            const float4* pC = (const float4*)(CT + bcbase + (size_t)s * 1024);
            #pragma unroll
            for (int c = 0; c < 4; ++c) {
                float4 bv = pB[c], cv = pC[c];
                Bv[c * 4 + 0] = bv.x; Bv[c * 4 + 1] = bv.y; Bv[c * 4 + 2] = bv.z; Bv[c * 4 + 3] = bv.w;
                Cv[c * 4 + 0] = cv.x; Cv[c * 4 + 1] = cv.y; Cv[c * 4 + 2] = cv.z; Cv[c * 4 + 3] = cv.w;
            }
        }
        float h = 0.f, P = 1.f;
        #pragma unroll
        for (int i = 0; i < 16; ++i) {
            float a = __builtin_amdgcn_exp2f(dt[i] * A2);
            h = a * h + du[i] * Bv[i];
            P *= a;
            y[i] += h * Cv[i];
            PC[i] = P * Cv[i];
        }
        // inclusive Kogge-Stone over segment transforms (A=prod, E=end-state)
        float Aagg = P, E = h;
        #pragma unroll
        for (int dlt = 1; dlt < 64; dlt <<= 1) {
            float Au = __shfl_up(Aagg, dlt, 64);
            float Eu = __shfl_up(E, dlt, 64);
            if (lane >= dlt) { E = Aagg * Eu + E; Aagg *= Au; }
        }
        float carry = __shfl_up(E, 1, 64);
        if (lane == 0) carry = 0.f;
        #pragma unroll
        for (int i = 0; i < 16; ++i) y[i] += carry * PC[i];
    }

    // epilogue: gate with u*D and silu(z), write yT
    float Dv = Dp[d];
    const float4* qu = (const float4*)(uT + base);
    size_t zrow = ((size_t)b * 1024 + lane * 16) * 512 + 256 + d;
    float* dst = yT + base;
    #pragma unroll
    for (int c = 0; c < 4; ++c) {
        float4 uv = qu[c];
        float ua[4] = {uv.x, uv.y, uv.z, uv.w};
        float r[4];
        #pragma unroll
        for (int i = 0; i < 4; ++i) {
            int ii = c * 4 + i;
            float z = xz[zrow + (size_t)ii * 512];
            r[i] = (y[ii] + ua[i] * Dv) * silu_f(z);
        }
        *(float4*)(dst + c * 4) = make_float4(r[0], r[1], r[2], r[3]);
    }
}

// ---------------------------------------------------------------- final projection (C_OUT=7)
__global__ __launch_bounds__(256) void outproj_kernel(
        const float* __restrict__ x, const float* __restrict__ W,
        float* __restrict__ out) {
    int wv = threadIdx.x >> 6, lane = threadIdx.x & 63;
    size_t m = (size_t)blockIdx.x * 4 + wv;
    float x0 = x[m * 128 + lane], x1 = x[m * 128 + lane + 64];
    #pragma unroll
    for (int c = 0; c < 7; ++c) {
        float p = x0 * W[c * 128 + lane] + x1 * W[c * 128 + lane + 64];
        #pragma unroll
        for (int o = 1; o < 64; o <<= 1) p += __shfl_xor(p, o, 64);
        if (lane == 0) out[m * 7 + c] = p;
    }
}

// ================================================================ launch
extern "C" void kernel_launch(void* const* d_in, const int* in_sizes, int n_in,
                              void* d_out, int out_size, void* d_ws, size_t ws_size,
                              hipStream_t stream) {
    const float* x_enc  = (const float*)d_in[0];
    const float* x_mark = (const float*)d_in[1];
    const float* tokW   = (const float*)d_in[4];
    const float* tempW  = (const float*)d_in[5];
    const float* norm_w = (const float*)d_in[6];
    const float* norm_b = (const float*)d_in[7];
    const float* inW    = (const float*)d_in[8];
    const float* convW  = (const float*)d_in[9];
    const float* convB  = (const float*)d_in[10];
    const float* xpW    = (const float*)d_in[11];
    const float* dtW    = (const float*)d_in[12];
    const float* dtbp   = (const float*)d_in[13];
    const float* A_log  = (const float*)d_in[14];
    const float* Dp     = (const float*)d_in[15];
    const float* outW   = (const float*)d_in[16];
    const float* nfw    = (const float*)d_in[17];
    const float* nfb    = (const float*)d_in[18];
    const float* finW   = (const float*)d_in[19];
    float* out = (float*)d_out;

    float* ws = (float*)d_ws;
    size_t o = 0;
    float* hidden   = ws + o; o += (size_t)M_ * DM;    // 4.19M
    float* residual = ws + o; o += (size_t)M_ * DM;    // 4.19M
    float* xln      = ws + o; o += (size_t)M_ * DM;    // 4.19M (also hosts BT/CT after in_proj)
    float* xz       = ws + o; o += (size_t)M_ * 512;   // 16.8M
    float* uT       = ws + o; o += (size_t)M_ * DI;    // 8.39M
    float* dbc      = ws + o; o += (size_t)M_ * 40;    // 1.31M
    float* dtT      = ws + o; o += (size_t)M_ * DI;    // 8.39M
    float* yT       = ws + o; o += (size_t)M_ * DI;    // 8.39M
    float* BT = xln;                                   // alias: xln dead after in_proj GEMM
    float* CT = xln + (size_t)B_ * DS * L_;

    dim3 blk(256);
    embed_kernel<<<M_ * DM / 256, blk, 0, stream>>>(x_enc, x_mark, tokW, tempW, hidden);

    for (int l = 0; l < NL; ++l) {
        ln_kernel<<<M_ / 4, blk, 0, stream>>>(hidden, l ? residual : nullptr,
                                              norm_w + l * DM, norm_b + l * DM,
                                              xln, residual);
        // xz = xln @ in_W^T   (M x 512, K=128)
        gemm_nt_128<<<dim3(512 / 128, M_ / 128), blk, 0, stream>>>(
            xln, inW + (size_t)l * 512 * DM, xz, M_, 512, DM);
        // uT = silu(causal depthwise conv(xz[...,:256]))^T
        conv_uT_kernel<<<B_ * 16 * 4, blk, 0, stream>>>(xz, convW + l * DI * DC,
                                                        convB + l * DI, uT);
        // dbc = u @ xp_W^T    (M x 40, K=256), A transposed
        gemm_tn_64<<<dim3(1, M_ / 64), blk, 0, stream>>>(
            uT, xpW + (size_t)l * 40 * DI, dbc, M_, 40, DI);
        // dtT = softplus(dbc[:,:8] @ dtW^T + dtb)^T
        dtT_kernel<<<M_ / 64, blk, 0, stream>>>(dbc, dtW + l * DI * DR, dtbp + l * DI, dtT);
        // BT/CT = transpose of dbc[:, 8:24], dbc[:, 24:40]
        tbc_kernel<<<B_ * 8, blk, 0, stream>>>(dbc, BT, CT);
        // scan + gate -> yT
        scan2_kernel<<<B_ * DI / 4, blk, 0, stream>>>(dtT, uT, BT, CT,
                                                      A_log + l * DI * DS, xz,
                                                      Dp + l * DI, yT);
        // hidden = y @ out_W^T  (M x 128, K=256), A transposed
        gemm_tn_128<<<dim3(1, M_ / 128), blk, 0, stream>>>(
            yT, outW + (size_t)l * DM * DI, hidden, M_, DM, DI);
    }

    ln_kernel<<<M_ / 4, blk, 0, stream>>>(hidden, residual, nfw, nfb, xln, nullptr);
    outproj_kernel<<<M_ / 4, blk, 0, stream>>>(xln, finW, out);
}

// Round 3
// 794.772 us; speedup vs baseline: 1.5946x; 1.0852x over previous
//
#include <hip/hip_runtime.h>
#include <math.h>

#define B_  32
#define L_  1024
#define M_  (B_*L_)      // 32768 rows
#define DM  128
#define DI  256
#define DS  16
#define DC  4
#define DR  8
#define NL  2

__device__ __forceinline__ float silu_f(float x) { return x / (1.f + expf(-x)); }
__device__ __forceinline__ float softplus_f(float x) {
    return fmaxf(x, 0.f) + log1pf(expf(-fabsf(x)));
}

// ---------------------------------------------------------------- embed
__global__ __launch_bounds__(256) void embed_kernel(
        const float* __restrict__ x_enc, const float* __restrict__ x_mark,
        const float* __restrict__ tokW, const float* __restrict__ tempW,
        float* __restrict__ out) {
    int idx = blockIdx.x * 256 + threadIdx.x;      // over M_*DM
    int d = idx & 127;
    int m = idx >> 7;
    int b = m >> 10, t = m & 1023;
    const float* xb = x_enc + (size_t)b * L_ * 7;
    float acc = 0.f;
    #pragma unroll
    for (int w = 0; w < 3; ++w) {
        int tt = t + w - 1;
        tt = (tt < 0) ? (L_ - 1) : (tt >= L_ ? 0 : tt);   // circular pad
        const float* xr = xb + tt * 7;
        #pragma unroll
        for (int f = 0; f < 7; ++f) acc += xr[f] * tokW[(d * 7 + f) * 3 + w];
    }
    const float* mr = x_mark + (size_t)m * 4;
    #pragma unroll
    for (int f = 0; f < 4; ++f) acc += mr[f] * tempW[d * 4 + f];
    int i2 = d & ~1;
    float div = expf(-0.07195578415606394f * (float)i2);  // -ln(10000)/128
    float ang = (float)t * div;
    acc += (d & 1) ? cosf(ang) : sinf(ang);
    out[idx] = acc;
}

// ---------------------------------------------------------------- layernorm
__global__ __launch_bounds__(256) void ln_kernel(
        const float* __restrict__ a, const float* __restrict__ b,
        const float* __restrict__ w, const float* __restrict__ bias,
        float* __restrict__ out_ln, float* __restrict__ out_res) {
    int wv = threadIdx.x >> 6, lane = threadIdx.x & 63;
    size_t m = (size_t)blockIdx.x * 4 + wv;
    size_t base = m * DM;
    float x0 = a[base + lane], x1 = a[base + lane + 64];
    if (b) { x0 += b[base + lane]; x1 += b[base + lane + 64]; }
    if (out_res) { out_res[base + lane] = x0; out_res[base + lane + 64] = x1; }
    float s = x0 + x1;
    #pragma unroll
    for (int o = 1; o < 64; o <<= 1) s += __shfl_xor(s, o, 64);
    float mu = s * (1.f / 128.f);
    float d0 = x0 - mu, d1 = x1 - mu;
    float v = d0 * d0 + d1 * d1;
    #pragma unroll
    for (int o = 1; o < 64; o <<= 1) v += __shfl_xor(v, o, 64);
    float inv = rsqrtf(v * (1.f / 128.f) + 1e-5f);
    out_ln[base + lane]      = d0 * inv * w[lane]      + bias[lane];
    out_ln[base + lane + 64] = d1 * inv * w[lane + 64] + bias[lane + 64];
}

// ---------------------------------------------------------------- in_proj GEMM with split epilogue
// xz[m,n] = sum_k xln[m,k]*inW[n,k], K=128, N=512.
// n<256  -> xi[m*256+n]
// n>=256 -> zsilT[(b*256+(n-256))*1024 + t] = silu(val)   (transposed!)
__global__ __launch_bounds__(256) void gemm_inproj(
        const float* __restrict__ A, const float* __restrict__ W,
        float* __restrict__ xi, float* __restrict__ zsilT) {
    __shared__ float As[16][128];
    __shared__ float Ws[16][128];
    int bm = blockIdx.y * 128, bn = blockIdx.x * 128;
    int tid = threadIdx.x, tx = tid & 15, ty = tid >> 4;
    float acc[8][8] = {};
    for (int k0 = 0; k0 < 128; k0 += 16) {
        #pragma unroll
        for (int i = 0; i < 2; ++i) {
            int idx = tid * 2 + i;            // 0..511
            int row = idx >> 2, c4 = (idx & 3) * 4;
            float4 a4 = *(const float4*)(A + (size_t)(bm + row) * 128 + k0 + c4);
            As[c4 + 0][row] = a4.x; As[c4 + 1][row] = a4.y;
            As[c4 + 2][row] = a4.z; As[c4 + 3][row] = a4.w;
            float4 w4 = *(const float4*)(W + (size_t)(bn + row) * 128 + k0 + c4);
            Ws[c4 + 0][row] = w4.x; Ws[c4 + 1][row] = w4.y;
            Ws[c4 + 2][row] = w4.z; Ws[c4 + 3][row] = w4.w;
        }
        __syncthreads();
        #pragma unroll
        for (int k = 0; k < 16; ++k) {
            float a[8], bb[8];
            *(float4*)&a[0]  = *(float4*)&As[k][ty * 8];
            *(float4*)&a[4]  = *(float4*)&As[k][ty * 8 + 4];
            *(float4*)&bb[0] = *(float4*)&Ws[k][tx * 8];
            *(float4*)&bb[4] = *(float4*)&Ws[k][tx * 8 + 4];
            #pragma unroll
            for (int i = 0; i < 8; ++i)
                #pragma unroll
                for (int j = 0; j < 8; ++j) acc[i][j] += a[i] * bb[j];
        }
        __syncthreads();
    }
    if (bn < 256) {
        #pragma unroll
        for (int i = 0; i < 8; ++i) {
            size_t row = (size_t)(bm + ty * 8 + i) * 256 + bn + tx * 8;
            *(float4*)(xi + row)     = *(float4*)&acc[i][0];
            *(float4*)(xi + row + 4) = *(float4*)&acc[i][4];
        }
    } else {
        int b = bm >> 10, t0 = (bm & 1023) + ty * 8;
        #pragma unroll
        for (int j = 0; j < 8; ++j) {
            int zd = bn - 256 + tx * 8 + j;
            float r[8];
            #pragma unroll
            for (int i = 0; i < 8; ++i) r[i] = silu_f(acc[i][j]);
            float* dst = zsilT + ((size_t)(b * 256 + zd)) * 1024 + t0;
            *(float4*)dst       = *(float4*)&r[0];
            *(float4*)(dst + 4) = *(float4*)&r[4];
        }
    }
}

// ---------------------------------------------------------------- GEMM 128x128 (A transposed: AT[(b*K)+e][t])
__global__ __launch_bounds__(256) void gemm_tn_128(
        const float* __restrict__ AT, const float* __restrict__ W,
        float* __restrict__ C, int M, int N, int K) {
    __shared__ float As[16][128];
    __shared__ float Ws[16][128];
    int bm = blockIdx.y * 128, bn = blockIdx.x * 128;
    int b = bm >> 10, tloc = bm & 1023;
    int tid = threadIdx.x, tx = tid & 15, ty = tid >> 4;
    float acc[8][8] = {};
    for (int k0 = 0; k0 < K; k0 += 16) {
        #pragma unroll
        for (int i = 0; i < 2; ++i) {
            int idx = tid * 2 + i;            // 0..511
            int k = idx >> 5, m4 = (idx & 31) * 4;
            float4 a4 = *(const float4*)(AT + ((size_t)b * K + k0 + k) * 1024 + tloc + m4);
            *(float4*)&As[k][m4] = a4;
            int row = idx >> 2, c4 = (idx & 3) * 4;
            float4 w4 = *(const float4*)(W + (size_t)(bn + row) * K + k0 + c4);
            Ws[c4 + 0][row] = w4.x; Ws[c4 + 1][row] = w4.y;
            Ws[c4 + 2][row] = w4.z; Ws[c4 + 3][row] = w4.w;
        }
        __syncthreads();
        #pragma unroll
        for (int k = 0; k < 16; ++k) {
            float a[8], bb[8];
            *(float4*)&a[0]  = *(float4*)&As[k][ty * 8];
            *(float4*)&a[4]  = *(float4*)&As[k][ty * 8 + 4];
            *(float4*)&bb[0] = *(float4*)&Ws[k][tx * 8];
            *(float4*)&bb[4] = *(float4*)&Ws[k][tx * 8 + 4];
            #pragma unroll
            for (int i = 0; i < 8; ++i)
                #pragma unroll
                for (int j = 0; j < 8; ++j) acc[i][j] += a[i] * bb[j];
        }
        __syncthreads();
    }
    #pragma unroll
    for (int i = 0; i < 8; ++i) {
        size_t row = (size_t)(bm + ty * 8 + i) * N + bn + tx * 8;
        *(float4*)(C + row)     = *(float4*)&acc[i][0];
        *(float4*)(C + row + 4) = *(float4*)&acc[i][4];
    }
}

// ---------------------------------------------------------------- GEMM 64x64 (A transposed), N small w/ guard
__global__ __launch_bounds__(256) void gemm_tn_64(
        const float* __restrict__ AT, const float* __restrict__ W,
        float* __restrict__ C, int M, int N, int K) {
    __shared__ float As[16][68];
    __shared__ float Ws[16][68];
    int bm = blockIdx.y * 64, bn = blockIdx.x * 64;
    int b = bm >> 10, tloc = bm & 1023;
    int tid = threadIdx.x, tx = tid & 15, ty = tid >> 4;
    float acc[4][4] = {};
    for (int k0 = 0; k0 < K; k0 += 16) {
        {
            int k = tid >> 4, m4 = (tid & 15) * 4;
            float4 a4 = *(const float4*)(AT + ((size_t)b * K + k0 + k) * 1024 + tloc + m4);
            *(float4*)&As[k][m4] = a4;
        }
        #pragma unroll
        for (int i = 0; i < 4; ++i) {
            int r = i * 16 + ty;
            int n = bn + r;
            Ws[tx][r] = (n < N) ? W[(size_t)n * K + k0 + tx] : 0.f;
        }
        __syncthreads();
        #pragma unroll
        for (int k = 0; k < 16; ++k) {
            float a[4], bb[4];
            #pragma unroll
            for (int i = 0; i < 4; ++i) a[i] = As[k][ty * 4 + i];
            #pragma unroll
            for (int j = 0; j < 4; ++j) bb[j] = Ws[k][tx * 4 + j];
            #pragma unroll
            for (int i = 0; i < 4; ++i)
                #pragma unroll
                for (int j = 0; j < 4; ++j) acc[i][j] += a[i] * bb[j];
        }
        __syncthreads();
    }
    #pragma unroll
    for (int i = 0; i < 4; ++i) {
        int m = bm + ty * 4 + i;
        #pragma unroll
        for (int j = 0; j < 4; ++j) {
            int n = bn + tx * 4 + j;
            if (n < N) C[(size_t)m * N + n] = acc[i][j];
        }
    }
}

// ---------------------------------------------------------------- conv + silu -> uT  (xi row-stride 256)
__global__ __launch_bounds__(256) void conv_uT_kernel(
        const float* __restrict__ xi, const float* __restrict__ cw,
        const float* __restrict__ cb, float* __restrict__ uT) {
    __shared__ float xs[67][64];
    int bx = blockIdx.x;
    int d0 = (bx & 3) * 64;
    int t0 = ((bx >> 2) & 15) * 64;
    int b = bx >> 6;
    int tid = threadIdx.x;
    {
        int row = tid >> 2, q = tid & 3;
        int t = t0 - 3 + row;
        const float* src = xi + ((size_t)(b * 1024 + t)) * 256 + d0 + q * 16;
        #pragma unroll
        for (int j = 0; j < 4; ++j) {
            float4 v = (t >= 0) ? *(const float4*)(src + j * 4)
                                : make_float4(0.f, 0.f, 0.f, 0.f);
            *(float4*)&xs[row][q * 16 + j * 4] = v;
        }
        if (tid < 12) {
            int row2 = 64 + (tid >> 2);
            int t2 = t0 - 3 + row2;               // >= 61, always valid
            const float* s2 = xi + ((size_t)(b * 1024 + t2)) * 256 + d0 + q * 16;
            #pragma unroll
            for (int j = 0; j < 4; ++j)
                *(float4*)&xs[row2][q * 16 + j * 4] = *(const float4*)(s2 + j * 4);
        }
    }
    __syncthreads();
    int dl = tid & 63, tl = tid >> 6;
    float4 w4 = ((const float4*)cw)[d0 + dl];
    float bias = cb[d0 + dl];
    float* dst = uT + ((size_t)(b * 256 + d0 + dl)) * 1024 + t0 + tl * 16;
    #pragma unroll
    for (int c = 0; c < 4; ++c) {
        float r[4];
        #pragma unroll
        for (int i = 0; i < 4; ++i) {
            int tt = tl * 16 + c * 4 + i;
            float acc = bias + xs[tt][dl] * w4.x + xs[tt + 1][dl] * w4.y
                             + xs[tt + 2][dl] * w4.z + xs[tt + 3][dl] * w4.w;
            r[i] = silu_f(acc);
        }
        *(float4*)(dst + c * 4) = make_float4(r[0], r[1], r[2], r[3]);
    }
}

// ---------------------------------------------------------------- dt proj + softplus -> dtT
__global__ __launch_bounds__(256) void dtT_kernel(
        const float* __restrict__ dbc, const float* __restrict__ dtW,
        const float* __restrict__ dtb, float* __restrict__ dtT) {
    int n = threadIdx.x;
    int m0 = blockIdx.x * 64;
    int b = m0 >> 10, t0 = m0 & 1023;
    float4 wa = ((const float4*)dtW)[n * 2];
    float4 wb = ((const float4*)dtW)[n * 2 + 1];
    float bias = dtb[n];
    float* dst = dtT + ((size_t)(b * 256 + n)) * 1024 + t0;
    for (int r4 = 0; r4 < 64; r4 += 4) {
        float o[4];
        #pragma unroll
        for (int i = 0; i < 4; ++i) {
            const float* row = dbc + (size_t)(m0 + r4 + i) * 40;
            float acc = bias + row[0] * wa.x + row[1] * wa.y + row[2] * wa.z + row[3] * wa.w
                             + row[4] * wb.x + row[5] * wb.y + row[6] * wb.z + row[7] * wb.w;
            o[i] = softplus_f(acc);
        }
        *(float4*)(dst + r4) = make_float4(o[0], o[1], o[2], o[3]);
    }
}

// ---------------------------------------------------------------- dbc -> BT, CT (transpose)
__global__ __launch_bounds__(256) void tbc_kernel(
        const float* __restrict__ dbc, float* __restrict__ BT, float* __restrict__ CT) {
    __shared__ float tile[128][33];
    int b = blockIdx.x >> 3, t0 = (blockIdx.x & 7) * 128;
    int tid = threadIdx.x;
    {
        int t = tid >> 1, half = tid & 1;
        const float* src = dbc + (size_t)(b * 1024 + t0 + t) * 40 + 8 + half * 16;
        #pragma unroll
        for (int c = 0; c < 4; ++c) {
            float4 v = *(const float4*)(src + c * 4);
            int c0 = half * 16 + c * 4;
            tile[t][c0 + 0] = v.x; tile[t][c0 + 1] = v.y;
            tile[t][c0 + 2] = v.z; tile[t][c0 + 3] = v.w;
        }
    }
    __syncthreads();
    int row = tid >> 3, q = tid & 7;
    float* dst = ((row < 16) ? BT : CT) + ((size_t)(b * 16 + (row & 15))) * 1024 + t0 + q * 16;
    #pragma unroll
    for (int c = 0; c < 4; ++c) {
        int i0 = q * 16 + c * 4;
        float4 w = make_float4(tile[i0][row], tile[i0 + 1][row],
                               tile[i0 + 2][row], tile[i0 + 3][row]);
        *(float4*)(dst + c * 4) = w;
    }
}

// ---------------------------------------------------------------- scan v3
// 512 thr = 8 waves = 8 d-channels of one b. Per s: block stages B/C rows in LDS.
// Lane owns 16 timesteps; Kogge-Stone segment combine across 64 lanes.
// Epilogue fuses gate: yT = (y + u*D) * zsilT (pre-silu'd z, transposed).
__global__ __launch_bounds__(512) void scan3_kernel(
        const float* __restrict__ dtT, const float* __restrict__ uT,
        const float* __restrict__ BT, const float* __restrict__ CT,
        const float* __restrict__ A_log, const float* __restrict__ zsilT,
        const float* __restrict__ Dp, float* __restrict__ yT) {
    __shared__ float4 sB[4][64], sC[4][64];
    int wv = threadIdx.x >> 6, lane = threadIdx.x & 63;
    int b = blockIdx.x >> 5;
    int d = (blockIdx.x & 31) * 8 + wv;
    size_t base = ((size_t)(b * 256 + d)) * 1024 + lane * 16;

    float dt[16], u[16], y[16], PC[16];
    {
        const float4* p = (const float4*)(dtT + base);
        const float4* q = (const float4*)(uT + base);
        #pragma unroll
        for (int c = 0; c < 4; ++c) {
            float4 dv = p[c], uv = q[c];
            *(float4*)&dt[c * 4] = dv;
            *(float4*)&u[c * 4]  = uv;
        }
        #pragma unroll
        for (int i = 0; i < 16; ++i) y[i] = 0.f;
    }
    const float4* BT4 = (const float4*)BT + (size_t)b * 16 * 256;
    const float4* CT4 = (const float4*)CT + (size_t)b * 16 * 256;

    for (int s = 0; s < 16; ++s) {
        __syncthreads();          // previous iteration's LDS reads done
        {
            int w = threadIdx.x;
            if (w < 256) sB[w & 3][w >> 2] = BT4[s * 256 + w];
            else { int w2 = w - 256; sC[w2 & 3][w2 >> 2] = CT4[s * 256 + w2]; }
        }
        __syncthreads();
        float A2 = -expf(A_log[d * 16 + s]) * 1.4426950408889634f;  // A*log2(e)
        float h = 0.f, P = 1.f;
        #pragma unroll
        for (int c = 0; c < 4; ++c) {
            float Bv[4], Cv[4];
            *(float4*)Bv = sB[c][lane];
            *(float4*)Cv = sC[c][lane];
            #pragma unroll
            for (int i = 0; i < 4; ++i) {
                int ii = c * 4 + i;
                float a = __builtin_amdgcn_exp2f(dt[ii] * A2);
                h = a * h + dt[ii] * u[ii] * Bv[i];
                P *= a;
                y[ii] += h * Cv[i];
                PC[ii] = P * Cv[i];
            }
        }
        // inclusive Kogge-Stone over segment transforms (A=prod, E=end-state)
        float Aagg = P, E = h;
        #pragma unroll
        for (int dlt = 1; dlt < 64; dlt <<= 1) {
            float Au = __shfl_up(Aagg, dlt, 64);
            float Eu = __shfl_up(E, dlt, 64);
            if (lane >= dlt) { E = Aagg * Eu + E; Aagg *= Au; }
        }
        float carry = __shfl_up(E, 1, 64);
        if (lane == 0) carry = 0.f;
        #pragma unroll
        for (int i = 0; i < 16; ++i) y[i] += carry * PC[i];
    }

    // epilogue: gate with u*D and pre-silu'd z, write yT
    float Dv = Dp[d];
    const float4* qz = (const float4*)(zsilT + base);
    float* dst = yT + base;
    #pragma unroll
    for (int c = 0; c < 4; ++c) {
        float4 zv = qz[c];
        float za[4] = {zv.x, zv.y, zv.z, zv.w};
        float r[4];
        #pragma unroll
        for (int i = 0; i < 4; ++i) {
            int ii = c * 4 + i;
            r[i] = (y[ii] + u[ii] * Dv) * za[i];
        }
        *(float4*)(dst + c * 4) = make_float4(r[0], r[1], r[2], r[3]);
    }
}

// ---------------------------------------------------------------- final projection (C_OUT=7)
__global__ __launch_bounds__(256) void outproj_kernel(
        const float* __restrict__ x, const float* __restrict__ W,
        float* __restrict__ out) {
    int wv = threadIdx.x >> 6, lane = threadIdx.x & 63;
    size_t m = (size_t)blockIdx.x * 4 + wv;
    float x0 = x[m * 128 + lane], x1 = x[m * 128 + lane + 64];
    #pragma unroll
    for (int c = 0; c < 7; ++c) {
        float p = x0 * W[c * 128 + lane] + x1 * W[c * 128 + lane + 64];
        #pragma unroll
        for (int o = 1; o < 64; o <<= 1) p += __shfl_xor(p, o, 64);
        if (lane == 0) out[m * 7 + c] = p;
    }
}

// ================================================================ launch
extern "C" void kernel_launch(void* const* d_in, const int* in_sizes, int n_in,
                              void* d_out, int out_size, void* d_ws, size_t ws_size,
                              hipStream_t stream) {
    const float* x_enc  = (const float*)d_in[0];
    const float* x_mark = (const float*)d_in[1];
    const float* tokW   = (const float*)d_in[4];
    const float* tempW  = (const float*)d_in[5];
    const float* norm_w = (const float*)d_in[6];
    const float* norm_b = (const float*)d_in[7];
    const float* inW    = (const float*)d_in[8];
    const float* convW  = (const float*)d_in[9];
    const float* convB  = (const float*)d_in[10];
    const float* xpW    = (const float*)d_in[11];
    const float* dtW    = (const float*)d_in[12];
    const float* dtbp   = (const float*)d_in[13];
    const float* A_log  = (const float*)d_in[14];
    const float* Dp     = (const float*)d_in[15];
    const float* outW   = (const float*)d_in[16];
    const float* nfw    = (const float*)d_in[17];
    const float* nfb    = (const float*)d_in[18];
    const float* finW   = (const float*)d_in[19];
    float* out = (float*)d_out;

    float* ws = (float*)d_ws;
    size_t o = 0;
    float* hidden   = ws + o; o += (size_t)M_ * DM;    // 4.19M floats
    float* residual = ws + o; o += (size_t)M_ * DM;
    float* xln      = ws + o; o += (size_t)M_ * DM;    // also hosts BT/CT
    float* xi       = ws + o; o += (size_t)M_ * DI;    // in_proj x-half
    float* zsilT    = ws + o; o += (size_t)M_ * DI;    // silu(z), transposed
    float* uT       = ws + o; o += (size_t)M_ * DI;
    float* dbc      = ws + o; o += (size_t)M_ * 40;
    float* dtT      = ws + o; o += (size_t)M_ * DI;
    float* yT       = ws + o; o += (size_t)M_ * DI;
    float* BT = xln;                                   // alias: xln dead after in_proj
    float* CT = xln + (size_t)B_ * DS * L_;

    dim3 blk(256);
    embed_kernel<<<M_ * DM / 256, blk, 0, stream>>>(x_enc, x_mark, tokW, tempW, hidden);

    for (int l = 0; l < NL; ++l) {
        ln_kernel<<<M_ / 4, blk, 0, stream>>>(hidden, l ? residual : nullptr,
                                              norm_w + l * DM, norm_b + l * DM,
                                              xln, residual);
        // in_proj: xi (cols<256) + silu(z) transposed (cols>=256)
        gemm_inproj<<<dim3(4, M_ / 128), blk, 0, stream>>>(
            xln, inW + (size_t)l * 512 * DM, xi, zsilT);
        // uT = silu(causal depthwise conv(xi))^T
        conv_uT_kernel<<<B_ * 16 * 4, blk, 0, stream>>>(xi, convW + l * DI * DC,
                                                        convB + l * DI, uT);
        // dbc = u @ xp_W^T    (M x 40, K=256), A transposed
        gemm_tn_64<<<dim3(1, M_ / 64), blk, 0, stream>>>(
            uT, xpW + (size_t)l * 40 * DI, dbc, M_, 40, DI);
        // dtT = softplus(dbc[:,:8] @ dtW^T + dtb)^T
        dtT_kernel<<<M_ / 64, blk, 0, stream>>>(dbc, dtW + l * DI * DR, dtbp + l * DI, dtT);
        // BT/CT = transpose of dbc[:, 8:24], dbc[:, 24:40]
        tbc_kernel<<<B_ * 8, blk, 0, stream>>>(dbc, BT, CT);
        // scan + gate -> yT
        scan3_kernel<<<B_ * 32, dim3(512), 0, stream>>>(dtT, uT, BT, CT,
                                                        A_log + l * DI * DS, zsilT,
                                                        Dp + l * DI, yT);
        // hidden = y @ out_W^T  (M x 128, K=256), A transposed
        gemm_tn_128<<<dim3(1, M_ / 128), blk, 0, stream>>>(
            yT, outW + (size_t)l * DM * DI, hidden, M_, DM, DI);
    }

    ln_kernel<<<M_ / 4, blk, 0, stream>>>(hidden, residual, nfw, nfb, xln, nullptr);
    outproj_kernel<<<M_ / 4, blk, 0, stream>>>(xln, finW, out);
}